// Round 1
// baseline (206.109 us; speedup 1.0000x reference)
//
#include <hip/hip_runtime.h>
#include <hip/hip_bf16.h>
#include <stdint.h>

typedef __bf16 bf16x8 __attribute__((ext_vector_type(8)));
typedef float  f32x4  __attribute__((ext_vector_type(4)));

// ---------- helpers ----------

// round-to-nearest-even f32 -> bf16 on raw bits; returns packed pair (hi<<16 | lo)
__device__ __forceinline__ uint32_t rn2_bf16(uint32_t lo, uint32_t hi) {
  uint32_t rlo = (lo + 0x7FFFu + ((lo >> 16) & 1u)) >> 16;
  uint32_t rhi = (hi + 0x7FFFu + ((hi >> 16) & 1u)) >> 16;
  return (rhi << 16) | (rlo & 0xFFFFu);
}

// sign(w) as bf16 (+1 = 0x3F80, -1 = 0xBF80, 0 -> 0), packed pair
__device__ __forceinline__ uint32_t sign2_bf16(uint32_t lo, uint32_t hi) {
  uint32_t slo = (lo & 0x7FFFFFFFu) ? (0x3F80u | ((lo >> 16) & 0x8000u)) : 0u;
  uint32_t shi = (hi & 0x7FFFFFFFu) ? (0x3F80u | ((hi >> 16) & 0x8000u)) : 0u;
  return (shi << 16) | slo;
}

__device__ __forceinline__ void gload_lds16(const uint16_t* g, uint16_t* l) {
  __builtin_amdgcn_global_load_lds(
      (const __attribute__((address_space(1))) uint32_t*)g,
      (__attribute__((address_space(3))) uint32_t*)l,
      16, 0, 0);
}

// ---------- prep kernels (memory-bound, vectorized 8 elems/thread/iter) ----------

__global__ void cvt_x_bf16(const uint4* __restrict__ in, uint4* __restrict__ out, int n8) {
  int stride = gridDim.x * blockDim.x;
  for (int i = blockIdx.x * blockDim.x + threadIdx.x; i < n8; i += stride) {
    uint4 a = in[2 * i + 0];
    uint4 b = in[2 * i + 1];
    uint4 o;
    o.x = rn2_bf16(a.x, a.y);
    o.y = rn2_bf16(a.z, a.w);
    o.z = rn2_bf16(b.x, b.y);
    o.w = rn2_bf16(b.z, b.w);
    out[i] = o;
  }
}

__global__ void cvt_w_sign(const uint4* __restrict__ in, uint4* __restrict__ out, int n8) {
  int stride = gridDim.x * blockDim.x;
  for (int i = blockIdx.x * blockDim.x + threadIdx.x; i < n8; i += stride) {
    uint4 a = in[2 * i + 0];
    uint4 b = in[2 * i + 1];
    uint4 o;
    o.x = sign2_bf16(a.x, a.y);
    o.y = sign2_bf16(a.z, a.w);
    o.z = sign2_bf16(b.x, b.y);
    o.w = sign2_bf16(b.z, b.w);
    out[i] = o;
  }
}

// ---------- bf16 GEMM: C[M][N] = A[M][K] * B[N][K]^T + bias ----------
// m97-structure: 128x128 tile, BK=32, 4 waves (2x2), global_load_lds width 16,
// mfma_f32_16x16x32_bf16, C/D layout col=lane&15, row=(lane>>4)*4+reg.

__global__ __launch_bounds__(256) void gemm_bin(
    const uint16_t* __restrict__ A,  // [M][K] bf16 bits
    const uint16_t* __restrict__ B,  // [N][K] bf16 bits
    const float* __restrict__ bias,  // [N]
    float* __restrict__ C,           // [M][N] f32
    int M, int N, int K) {
  constexpr int BM = 128, BN = 128, BK = 32;
  __shared__ alignas(16) uint16_t lA[BM * BK];
  __shared__ alignas(16) uint16_t lB[BN * BK];

  const int tid  = threadIdx.x;
  const int lane = tid & 63;
  const int wid  = tid >> 6;
  const int wr   = wid >> 1;      // wave row (0..1), 64-row stripe
  const int wc   = wid & 1;       // wave col (0..1), 64-col stripe
  const int r16  = lane & 15;
  const int kg   = lane >> 4;     // k-group 0..3

  const int m0 = blockIdx.y * BM;
  const int n0 = blockIdx.x * BN;

  f32x4 acc[4][4] = {};

  for (int k0 = 0; k0 < K; k0 += BK) {
    __syncthreads();  // previous tile fully consumed before overwrite
    // stage A,B tiles: 8 KiB each; 2 passes x 256 threads x 16 B
#pragma unroll
    for (int p = 0; p < 2; ++p) {
      int idx = p * 256 + tid;
      int row = idx >> 2;            // 4 chunks of 16B per 64B row (BK=32 bf16)
      int col = (idx & 3) * 8;
      // LDS dest: wave-uniform base; HW scatters lane*16B -> linear layout
      gload_lds16(A + (size_t)(m0 + row) * K + k0 + col, lA + p * 2048 + wid * 512);
      gload_lds16(B + (size_t)(n0 + row) * K + k0 + col, lB + p * 2048 + wid * 512);
    }
    __syncthreads();  // drains vmcnt (global_load_lds) per compiler barrier semantics

    bf16x8 af[4], bg[4];
#pragma unroll
    for (int i = 0; i < 4; ++i)
      af[i] = *reinterpret_cast<const bf16x8*>(lA + (wr * 64 + i * 16 + r16) * BK + kg * 8);
#pragma unroll
    for (int i = 0; i < 4; ++i)
      bg[i] = *reinterpret_cast<const bf16x8*>(lB + (wc * 64 + i * 16 + r16) * BK + kg * 8);

#pragma unroll
    for (int mi = 0; mi < 4; ++mi)
#pragma unroll
      for (int ni = 0; ni < 4; ++ni)
        acc[mi][ni] = __builtin_amdgcn_mfma_f32_16x16x32_bf16(af[mi], bg[ni], acc[mi][ni], 0, 0, 0);
  }

  // epilogue: + bias, f32 store. row=(lane>>4)*4+j, col=lane&15 within fragment
#pragma unroll
  for (int ni = 0; ni < 4; ++ni) {
    int col = n0 + wc * 64 + ni * 16 + r16;
    float bv = bias[col];
#pragma unroll
    for (int mi = 0; mi < 4; ++mi) {
      int row0 = m0 + wr * 64 + mi * 16 + kg * 4;
#pragma unroll
      for (int j = 0; j < 4; ++j)
        C[(size_t)(row0 + j) * N + col] = acc[mi][ni][j] + bv;
    }
  }
}

// ---------- naive f32 fallback (only if workspace is too small) ----------
__global__ void gemm_naive(const float* __restrict__ x, const float* __restrict__ w,
                           const float* __restrict__ b, float* __restrict__ out,
                           int M, int N, int K) {
  int n = blockIdx.x * blockDim.x + threadIdx.x;
  int m = blockIdx.y;
  if (n >= N || m >= M) return;
  float acc = 0.f;
  for (int k = 0; k < K; ++k) {
    float wv = w[(size_t)n * K + k];
    float s = (wv > 0.f) ? 1.f : ((wv < 0.f) ? -1.f : 0.f);
    acc += x[(size_t)m * K + k] * s;
  }
  out[(size_t)m * N + n] = acc + b[n];
}

extern "C" void kernel_launch(void* const* d_in, const int* in_sizes, int n_in,
                              void* d_out, int out_size, void* d_ws, size_t ws_size,
                              hipStream_t stream) {
  const float* x = (const float*)d_in[0];
  const float* w = (const float*)d_in[1];
  const float* b = (const float*)d_in[2];
  float* out = (float*)d_out;

  const int N = in_sizes[2];      // 4096
  const int K = in_sizes[1] / N;  // 2048
  const int M = in_sizes[0] / K;  // 8192

  const size_t need = ((size_t)M * K + (size_t)N * K) * sizeof(uint16_t);
  if (ws_size < need) {
    hipLaunchKernelGGL(gemm_naive, dim3((N + 255) / 256, M), dim3(256), 0, stream,
                       x, w, b, out, M, N, K);
    return;
  }

  uint16_t* Xb = (uint16_t*)d_ws;            // [M][K] bf16
  uint16_t* Wb = Xb + (size_t)M * K;         // [N][K] bf16 (sign values)

  int nx8 = (M * K) / 8;
  int nw8 = (N * K) / 8;
  hipLaunchKernelGGL(cvt_x_bf16, dim3(2048), dim3(256), 0, stream,
                     (const uint4*)x, (uint4*)Xb, nx8);
  hipLaunchKernelGGL(cvt_w_sign, dim3(2048), dim3(256), 0, stream,
                     (const uint4*)w, (uint4*)Wb, nw8);
  hipLaunchKernelGGL(gemm_bin, dim3(N / 128, M / 128), dim3(256), 0, stream,
                     Xb, Wb, b, out, M, N, K);
}

// Round 2
// 171.977 us; speedup vs baseline: 1.1985x; 1.1985x over previous
//
#include <hip/hip_runtime.h>
#include <hip/hip_bf16.h>
#include <stdint.h>

typedef __bf16 bf16x8 __attribute__((ext_vector_type(8)));
typedef float  f32x4  __attribute__((ext_vector_type(4)));

// ---------- helpers ----------

__device__ __forceinline__ uint32_t rn2_bf16(uint32_t lo, uint32_t hi) {
  uint32_t rlo = (lo + 0x7FFFu + ((lo >> 16) & 1u)) >> 16;
  uint32_t rhi = (hi + 0x7FFFu + ((hi >> 16) & 1u)) >> 16;
  return (rhi << 16) | (rlo & 0xFFFFu);
}

__device__ __forceinline__ uint32_t sign2_bf16(uint32_t lo, uint32_t hi) {
  uint32_t slo = (lo & 0x7FFFFFFFu) ? (0x3F80u | ((lo >> 16) & 0x8000u)) : 0u;
  uint32_t shi = (hi & 0x7FFFFFFFu) ? (0x3F80u | ((hi >> 16) & 0x8000u)) : 0u;
  return (shi << 16) | slo;
}

__device__ __forceinline__ void gl16(const void* g, void* l) {
  __builtin_amdgcn_global_load_lds(
      (const __attribute__((address_space(1))) uint32_t*)g,
      (__attribute__((address_space(3))) uint32_t*)l,
      16, 0, 0);
}

// ---------- prep kernels ----------

__global__ void cvt_x_bf16(const uint4* __restrict__ in, uint4* __restrict__ out, int n8) {
  int stride = gridDim.x * blockDim.x;
  for (int i = blockIdx.x * blockDim.x + threadIdx.x; i < n8; i += stride) {
    uint4 a = in[2 * i + 0];
    uint4 b = in[2 * i + 1];
    uint4 o;
    o.x = rn2_bf16(a.x, a.y);
    o.y = rn2_bf16(a.z, a.w);
    o.z = rn2_bf16(b.x, b.y);
    o.w = rn2_bf16(b.z, b.w);
    out[i] = o;
  }
}

__global__ void cvt_w_sign(const uint4* __restrict__ in, uint4* __restrict__ out, int n8) {
  int stride = gridDim.x * blockDim.x;
  for (int i = blockIdx.x * blockDim.x + threadIdx.x; i < n8; i += stride) {
    uint4 a = in[2 * i + 0];
    uint4 b = in[2 * i + 1];
    uint4 o;
    o.x = sign2_bf16(a.x, a.y);
    o.y = sign2_bf16(a.z, a.w);
    o.z = sign2_bf16(b.x, b.y);
    o.w = sign2_bf16(b.z, b.w);
    out[i] = o;
  }
}

// ---------- 256x256 8-phase GEMM (m201 template, plain HIP) ----------
// C[M][N] = A[M][K] * B[N][K]^T + bias.  BM=BN=256, BK=64, 8 waves (2Mx4N).
// LDS 128 KiB: buf d at d*65536; A tile [256][64]bf16 at +0 (two 16KB halves),
// B tile at +32768. st_16x32 swizzle: byte ^= ((byte>>9)&1)<<5, applied as
// pre-swizzled global source (gload_lds writes linearly) + swizzled ds_read.

#define BAR()   __builtin_amdgcn_s_barrier()
#define LGKM0() asm volatile("s_waitcnt lgkmcnt(0)" ::: "memory")
#define VM4()   asm volatile("s_waitcnt vmcnt(4)" ::: "memory")
#define SWZ(x)  ((x) ^ ((((x) >> 9) & 1) << 5))

__global__ __launch_bounds__(512, 2) void gemm256(
    const uint16_t* __restrict__ A,  // [M][K] bf16 bits
    const uint16_t* __restrict__ B,  // [N][K] bf16 bits (sign values)
    const float* __restrict__ bias,  // [N]
    float* __restrict__ C,           // [M][N] f32
    int M, int N, int K) {
  __shared__ alignas(16) uint8_t L[131072];
  uint8_t* Lb = L;

  const int tid  = threadIdx.x;
  const int lane = tid & 63;
  const int w    = tid >> 6;
  const int wr   = w >> 2;        // 0..1  -> M rows [wr*128, +128)
  const int wc   = w & 3;         // 0..3  -> N cols [wc*64, +64)
  const int r16  = lane & 15;
  const int kg   = lane >> 4;

  // bijective XCD swizzle (nwg % 8 == 0 guaranteed by launcher)
  const int nbx = N >> 8;
  const int nwg = nbx * (M >> 8);
  const int bid = blockIdx.x;
  const int swb = (bid & 7) * (nwg >> 3) + (bid >> 3);
  const size_t m0 = (size_t)(swb / nbx) << 8;
  const size_t n0 = (size_t)(swb % nbx) << 8;

  const int NT = K >> 6;              // BK=64 tiles
  const size_t rowB = (size_t)K * 2;  // global row stride in bytes

  // staging: per-lane pre-swizzled global source offsets (16B/lane, 2 instrs)
  const int o0 = (w << 10) + (lane << 4);
  const int o1 = o0 + 8192;
  const int s0 = SWZ(o0);
  const int s1 = SWZ(o1);
  const size_t g0 = (size_t)(s0 >> 7) * rowB + (s0 & 127);
  const size_t g1 = (size_t)(s1 >> 7) * rowB + (s1 & 127);
  const char* Ab = (const char*)A + m0 * rowB;
  const char* Bb = (const char*)B + n0 * rowB;
  const size_t hiO = (size_t)128 * rowB;  // +128 rows (second half)
  const int wB = w << 10;

  // fragment lane bases (bytes within a 32KB tile region)
  const int laneA = (wr * 128 + r16) * 128 + kg * 16;
  const int laneB = (wc * 64 + r16) * 128 + kg * 16;

#define STG(LOFF, SRC) do { \
    gl16((SRC) + g0, Lb + (LOFF) + wB); \
    gl16((SRC) + g1, Lb + (LOFF) + 8192 + wB); } while (0)

#define FRA(d, mi, ks) (*reinterpret_cast<const bf16x8*>( \
    Lb + (d) * 65536 + SWZ(laneA + (mi) * 2048 + (ks) * 64)))
#define FRB(d, ni, ks) (*reinterpret_cast<const bf16x8*>( \
    Lb + (d) * 65536 + 32768 + SWZ(laneB + (ni) * 2048 + (ks) * 64)))

  f32x4 acc[8][4] = {};

#define QMFMA(AARR, BARR, MB) do { \
    __builtin_amdgcn_s_setprio(1); \
    _Pragma("unroll") \
    for (int mi2 = 0; mi2 < 4; ++mi2) \
      _Pragma("unroll") \
      for (int ni = 0; ni < 4; ++ni) \
        acc[(MB) + mi2][ni] = __builtin_amdgcn_mfma_f32_16x16x32_bf16( \
            AARR[(MB) + mi2], BARR[ni], acc[(MB) + mi2][ni], 0, 0, 0); \
    __builtin_amdgcn_s_setprio(0); } while (0)

  // ---- prologue: tile0 -> buf0 (4 halves), tile1 A-halves -> buf1 ----
  STG(0,      Ab);
  STG(16384,  Ab + hiO);
  STG(32768,  Bb);
  STG(49152,  Bb + hiO);
  STG(65536,  Ab + 128);
  STG(81920,  Ab + hiO + 128);
  VM4();   // tile0's 8 loads landed; tile1's 4 still in flight
  BAR();

  bf16x8 a0[8], a1[8], b0[4], b1[4];
  const int T = K >> 7;  // iterations of 2 K-tiles
  for (int t = 0; t < T; ++t) {
    const size_t c1 = (size_t)(2 * t + 1) * 128;
    const int k2i = 2 * t + 2, k3i = 2 * t + 3;
    const size_t c2 = (size_t)(k2i < NT ? k2i : NT - 1) * 128;
    const size_t c3 = (size_t)(k3i < NT ? k3i : NT - 1) * 128;

    // ph1: read buf0 k0 frags; stage buf1 B-lo (tile 2t+1); Q1 = m-lo x k0
#pragma unroll
    for (int i = 0; i < 8; ++i) a0[i] = FRA(0, i, 0);
#pragma unroll
    for (int i = 0; i < 4; ++i) b0[i] = FRB(0, i, 0);
    STG(98304, Bb + c1);
    BAR(); LGKM0();
    QMFMA(a0, b0, 0);
    BAR();

    // ph2: read buf0 k1 frags; stage buf1 B-hi; Q2 = m-hi x k0
#pragma unroll
    for (int i = 0; i < 8; ++i) a1[i] = FRA(0, i, 1);
#pragma unroll
    for (int i = 0; i < 4; ++i) b1[i] = FRB(0, i, 1);
    STG(114688, Bb + hiO + c1);
    BAR(); LGKM0();
    QMFMA(a0, b0, 4);
    BAR();

    // ph3: stage buf0 A-lo (tile 2t+2); Q3 = m-lo x k1
    STG(0, Ab + c2);
    BAR(); LGKM0();
    QMFMA(a1, b1, 0);
    BAR();

    // ph4: stage buf0 A-hi; Q4 = m-hi x k1; counted vmcnt before buf1 reads
    STG(16384, Ab + hiO + c2);
    BAR(); LGKM0();
    QMFMA(a1, b1, 4);
    VM4();
    BAR();

    // ph5: read buf1 k0; stage buf0 B-lo (tile 2t+2); Q1
#pragma unroll
    for (int i = 0; i < 8; ++i) a0[i] = FRA(1, i, 0);
#pragma unroll
    for (int i = 0; i < 4; ++i) b0[i] = FRB(1, i, 0);
    STG(32768, Bb + c2);
    BAR(); LGKM0();
    QMFMA(a0, b0, 0);
    BAR();

    // ph6: read buf1 k1; stage buf0 B-hi; Q2
#pragma unroll
    for (int i = 0; i < 8; ++i) a1[i] = FRA(1, i, 1);
#pragma unroll
    for (int i = 0; i < 4; ++i) b1[i] = FRB(1, i, 1);
    STG(49152, Bb + hiO + c2);
    BAR(); LGKM0();
    QMFMA(a0, b0, 4);
    BAR();

    // ph7: stage buf1 A-lo (tile 2t+3); Q3
    STG(65536, Ab + c3);
    BAR(); LGKM0();
    QMFMA(a1, b1, 0);
    BAR();

    // ph8: stage buf1 A-hi; Q4; counted vmcnt before next buf0 reads
    STG(81920, Ab + hiO + c3);
    BAR(); LGKM0();
    QMFMA(a1, b1, 4);
    VM4();
    BAR();
  }

  // ---- epilogue: +bias, f32 store ----
#pragma unroll
  for (int ni = 0; ni < 4; ++ni) {
    const size_t col = n0 + wc * 64 + ni * 16 + r16;
    const float bv = bias[col];
#pragma unroll
    for (int mi = 0; mi < 8; ++mi) {
      const size_t row0 = m0 + wr * 128 + mi * 16 + kg * 4;
#pragma unroll
      for (int j = 0; j < 4; ++j)
        C[(row0 + j) * N + col] = acc[mi][ni][j] + bv;
    }
  }
}

// ---------- round-1 128x128 kernel (fallback, known-good) ----------

__global__ __launch_bounds__(256) void gemm_bin(
    const uint16_t* __restrict__ A, const uint16_t* __restrict__ B,
    const float* __restrict__ bias, float* __restrict__ C,
    int M, int N, int K) {
  constexpr int BK = 32;
  __shared__ alignas(16) uint16_t lA[128 * BK];
  __shared__ alignas(16) uint16_t lB[128 * BK];
  const int tid = threadIdx.x;
  const int lane = tid & 63;
  const int wid = tid >> 6;
  const int wr = wid >> 1, wc = wid & 1;
  const int r16 = lane & 15, kg = lane >> 4;
  const int m0 = blockIdx.y * 128, n0 = blockIdx.x * 128;
  f32x4 acc[4][4] = {};
  for (int k0 = 0; k0 < K; k0 += BK) {
    __syncthreads();
#pragma unroll
    for (int p = 0; p < 2; ++p) {
      int idx = p * 256 + tid;
      int row = idx >> 2;
      int col = (idx & 3) * 8;
      gl16(A + (size_t)(m0 + row) * K + k0 + col, lA + p * 2048 + wid * 512);
      gl16(B + (size_t)(n0 + row) * K + k0 + col, lB + p * 2048 + wid * 512);
    }
    __syncthreads();
    bf16x8 af[4], bg[4];
#pragma unroll
    for (int i = 0; i < 4; ++i)
      af[i] = *reinterpret_cast<const bf16x8*>(lA + (wr * 64 + i * 16 + r16) * BK + kg * 8);
#pragma unroll
    for (int i = 0; i < 4; ++i)
      bg[i] = *reinterpret_cast<const bf16x8*>(lB + (wc * 64 + i * 16 + r16) * BK + kg * 8);
#pragma unroll
    for (int mi = 0; mi < 4; ++mi)
#pragma unroll
      for (int ni = 0; ni < 4; ++ni)
        acc[mi][ni] = __builtin_amdgcn_mfma_f32_16x16x32_bf16(af[mi], bg[ni], acc[mi][ni], 0, 0, 0);
  }
#pragma unroll
  for (int ni = 0; ni < 4; ++ni) {
    int col = n0 + wc * 64 + ni * 16 + r16;
    float bv = bias[col];
#pragma unroll
    for (int mi = 0; mi < 4; ++mi) {
      int row0 = m0 + wr * 64 + mi * 16 + kg * 4;
#pragma unroll
      for (int j = 0; j < 4; ++j)
        C[(size_t)(row0 + j) * N + col] = acc[mi][ni][j] + bv;
    }
  }
}

__global__ void gemm_naive(const float* __restrict__ x, const float* __restrict__ w,
                           const float* __restrict__ b, float* __restrict__ out,
                           int M, int N, int K) {
  int n = blockIdx.x * blockDim.x + threadIdx.x;
  int m = blockIdx.y;
  if (n >= N || m >= M) return;
  float acc = 0.f;
  for (int k = 0; k < K; ++k) {
    float wv = w[(size_t)n * K + k];
    float s = (wv > 0.f) ? 1.f : ((wv < 0.f) ? -1.f : 0.f);
    acc += x[(size_t)m * K + k] * s;
  }
  out[(size_t)m * N + n] = acc + b[n];
}

extern "C" void kernel_launch(void* const* d_in, const int* in_sizes, int n_in,
                              void* d_out, int out_size, void* d_ws, size_t ws_size,
                              hipStream_t stream) {
  const float* x = (const float*)d_in[0];
  const float* w = (const float*)d_in[1];
  const float* b = (const float*)d_in[2];
  float* out = (float*)d_out;

  const int N = in_sizes[2];
  const int K = in_sizes[1] / N;
  const int M = in_sizes[0] / K;

  const size_t need = ((size_t)M * K + (size_t)N * K) * sizeof(uint16_t);
  if (ws_size < need) {
    hipLaunchKernelGGL(gemm_naive, dim3((N + 255) / 256, M), dim3(256), 0, stream,
                       x, w, b, out, M, N, K);
    return;
  }

  uint16_t* Xb = (uint16_t*)d_ws;
  uint16_t* Wb = Xb + (size_t)M * K;

  hipLaunchKernelGGL(cvt_x_bf16, dim3(2048), dim3(256), 0, stream,
                     (const uint4*)x, (uint4*)Xb, (M * K) / 8);
  hipLaunchKernelGGL(cvt_w_sign, dim3(2048), dim3(256), 0, stream,
                     (const uint4*)w, (uint4*)Wb, (N * K) / 8);

  const bool big_ok = (M % 256 == 0) && (N % 256 == 0) && (K % 128 == 0) &&
                      (((M / 256) * (N / 256)) % 8 == 0);
  if (big_ok) {
    hipLaunchKernelGGL(gemm256, dim3((M / 256) * (N / 256)), dim3(512), 0, stream,
                       Xb, Wb, b, out, M, N, K);
  } else {
    hipLaunchKernelGGL(gemm_bin, dim3(N / 128, M / 128), dim3(256), 0, stream,
                       Xb, Wb, b, out, M, N, K);
  }
}

// Round 3
// 156.549 us; speedup vs baseline: 1.3166x; 1.0985x over previous
//
#include <hip/hip_runtime.h>
#include <hip/hip_bf16.h>
#include <stdint.h>

typedef __bf16 bf16x8 __attribute__((ext_vector_type(8)));
typedef float  f32x4  __attribute__((ext_vector_type(4)));

// ---------- helpers ----------

__device__ __forceinline__ uint32_t rn2_bf16(uint32_t lo, uint32_t hi) {
  uint32_t rlo = (lo + 0x7FFFu + ((lo >> 16) & 1u)) >> 16;
  uint32_t rhi = (hi + 0x7FFFu + ((hi >> 16) & 1u)) >> 16;
  return (rhi << 16) | (rlo & 0xFFFFu);
}

__device__ __forceinline__ uint32_t sign2_bf16(uint32_t lo, uint32_t hi) {
  uint32_t slo = (lo & 0x7FFFFFFFu) ? (0x3F80u | ((lo >> 16) & 0x8000u)) : 0u;
  uint32_t shi = (hi & 0x7FFFFFFFu) ? (0x3F80u | ((hi >> 16) & 0x8000u)) : 0u;
  return (shi << 16) | slo;
}

__device__ __forceinline__ void gl16(const void* g, void* l) {
  __builtin_amdgcn_global_load_lds(
      (const __attribute__((address_space(1))) uint32_t*)g,
      (__attribute__((address_space(3))) uint32_t*)l,
      16, 0, 0);
}

// ---------- fused prep kernel: X -> bf16 (RN), W -> sign bf16 ----------

__global__ void cvt_prep(const uint4* __restrict__ x, uint4* __restrict__ xo, int nx8,
                         const uint4* __restrict__ w, uint4* __restrict__ wo, int nw8) {
  int stride = gridDim.x * blockDim.x;
  int total = nx8 + nw8;
  for (int i = blockIdx.x * blockDim.x + threadIdx.x; i < total; i += stride) {
    if (i < nx8) {
      uint4 a = x[2 * i + 0];
      uint4 b = x[2 * i + 1];
      uint4 o;
      o.x = rn2_bf16(a.x, a.y);
      o.y = rn2_bf16(a.z, a.w);
      o.z = rn2_bf16(b.x, b.y);
      o.w = rn2_bf16(b.z, b.w);
      xo[i] = o;
    } else {
      int j = i - nx8;
      uint4 a = w[2 * j + 0];
      uint4 b = w[2 * j + 1];
      uint4 o;
      o.x = sign2_bf16(a.x, a.y);
      o.y = sign2_bf16(a.z, a.w);
      o.z = sign2_bf16(b.x, b.y);
      o.w = sign2_bf16(b.z, b.w);
      wo[j] = o;
    }
  }
}

// ---------- 256x256 8-phase GEMM (m201 template, plain HIP) ----------
// C[M][N] = A[M][K] * B[N][K]^T + bias.  BM=BN=256, BK=64, 8 waves (2Mx4N).
// LDS 128 KiB: buf d at d*65536; A tile [256][64]bf16 at +0 (two 16KB halves),
// B tile at +32768.
// Swizzle: byte ^= ((byte>>7)&7)<<4  (chunk ^= row&7 within 128B rows) —
// full 3-bit spread so the 16 lanes of each kg-group cover all 8 chunks
// (2 lanes/bank = free, m136). Involution (bits 7-9 disjoint from 4-6);
// applied as pre-swizzled global source + swizzled ds_read (rule #21).

#define BAR()   __builtin_amdgcn_s_barrier()
#define LGKM0() asm volatile("s_waitcnt lgkmcnt(0)" ::: "memory")
#define VM4()   asm volatile("s_waitcnt vmcnt(4)" ::: "memory")
#define SWZ(x)  ((x) ^ ((((x) >> 7) & 7) << 4))

__global__ __launch_bounds__(512, 2) void gemm256(
    const uint16_t* __restrict__ A,  // [M][K] bf16 bits
    const uint16_t* __restrict__ B,  // [N][K] bf16 bits (sign values)
    const float* __restrict__ bias,  // [N]
    float* __restrict__ C,           // [M][N] f32
    int M, int N, int K) {
  __shared__ alignas(16) uint8_t L[131072];
  uint8_t* Lb = L;

  const int tid  = threadIdx.x;
  const int lane = tid & 63;
  const int w    = tid >> 6;
  const int wr   = w >> 2;        // 0..1  -> M rows [wr*128, +128)
  const int wc   = w & 3;         // 0..3  -> N cols [wc*64, +64)
  const int r16  = lane & 15;
  const int kg   = lane >> 4;

  // bijective XCD swizzle (nwg % 8 == 0 guaranteed by launcher)
  const int nbx = N >> 8;
  const int nwg = nbx * (M >> 8);
  const int bid = blockIdx.x;
  const int swb = (bid & 7) * (nwg >> 3) + (bid >> 3);
  const size_t m0 = (size_t)(swb / nbx) << 8;
  const size_t n0 = (size_t)(swb % nbx) << 8;

  const int NT = K >> 6;              // BK=64 tiles
  const size_t rowB = (size_t)K * 2;  // global row stride in bytes

  // staging: per-lane pre-swizzled global source offsets (16B/lane)
  const int o0 = (w << 10) + (lane << 4);
  const int o1 = o0 + 8192;
  const int s0 = SWZ(o0);
  const int s1 = SWZ(o1);
  const size_t g0 = (size_t)(s0 >> 7) * rowB + (s0 & 127);
  const size_t g1 = (size_t)(s1 >> 7) * rowB + (s1 & 127);
  const char* Ab = (const char*)A + m0 * rowB;
  const char* Bb = (const char*)B + n0 * rowB;
  const size_t hiO = (size_t)128 * rowB;  // +128 rows (second half)
  const int wB = w << 10;

  // fragment lane bases (bytes within a 32KB tile region)
  const int laneA = (wr * 128 + r16) * 128 + kg * 16;
  const int laneB = (wc * 64 + r16) * 128 + kg * 16;

#define STG(LOFF, SRC) do { \
    gl16((SRC) + g0, Lb + (LOFF) + wB); \
    gl16((SRC) + g1, Lb + (LOFF) + 8192 + wB); } while (0)

#define FRA(d, mi, ks) (*reinterpret_cast<const bf16x8*>( \
    Lb + (d) * 65536 + SWZ(laneA + (mi) * 2048 + (ks) * 64)))
#define FRB(d, ni, ks) (*reinterpret_cast<const bf16x8*>( \
    Lb + (d) * 65536 + 32768 + SWZ(laneB + (ni) * 2048 + (ks) * 64)))

  f32x4 acc[8][4] = {};

#define QMFMA(AARR, BARR, MB) do { \
    __builtin_amdgcn_s_setprio(1); \
    _Pragma("unroll") \
    for (int mi2 = 0; mi2 < 4; ++mi2) \
      _Pragma("unroll") \
      for (int ni = 0; ni < 4; ++ni) \
        acc[(MB) + mi2][ni] = __builtin_amdgcn_mfma_f32_16x16x32_bf16( \
            AARR[(MB) + mi2], BARR[ni], acc[(MB) + mi2][ni], 0, 0, 0); \
    __builtin_amdgcn_s_setprio(0); } while (0)

  // ---- prologue: tile0 -> buf0 (4 halves), tile1 A-halves -> buf1 ----
  STG(0,      Ab);
  STG(16384,  Ab + hiO);
  STG(32768,  Bb);
  STG(49152,  Bb + hiO);
  STG(65536,  Ab + 128);
  STG(81920,  Ab + hiO + 128);
  VM4();   // tile0's 8 loads landed; tile1's 4 still in flight
  BAR();

  bf16x8 a0[8], a1[8], b0[4], b1[4];
  const int T = K >> 7;  // iterations of 2 K-tiles
  for (int t = 0; t < T; ++t) {
    const size_t c1 = (size_t)(2 * t + 1) * 128;
    const int k2i = 2 * t + 2, k3i = 2 * t + 3;
    const size_t c2 = (size_t)(k2i < NT ? k2i : NT - 1) * 128;
    const size_t c3 = (size_t)(k3i < NT ? k3i : NT - 1) * 128;

    // ph1: read buf0 k0 frags; stage buf1 B-lo (tile 2t+1); Q1 = m-lo x k0
#pragma unroll
    for (int i = 0; i < 8; ++i) a0[i] = FRA(0, i, 0);
#pragma unroll
    for (int i = 0; i < 4; ++i) b0[i] = FRB(0, i, 0);
    STG(98304, Bb + c1);
    BAR(); LGKM0();
    QMFMA(a0, b0, 0);
    BAR();

    // ph2: read buf0 k1 frags; stage buf1 B-hi; Q2 = m-hi x k0
#pragma unroll
    for (int i = 0; i < 8; ++i) a1[i] = FRA(0, i, 1);
#pragma unroll
    for (int i = 0; i < 4; ++i) b1[i] = FRB(0, i, 1);
    STG(114688, Bb + hiO + c1);
    BAR(); LGKM0();
    QMFMA(a0, b0, 4);
    BAR();

    // ph3: stage buf0 A-lo (tile 2t+2); Q3 = m-lo x k1
    STG(0, Ab + c2);
    BAR(); LGKM0();
    QMFMA(a1, b1, 0);
    BAR();

    // ph4: stage buf0 A-hi; Q4 = m-hi x k1; counted vmcnt before buf1 reads
    STG(16384, Ab + hiO + c2);
    BAR(); LGKM0();
    QMFMA(a1, b1, 4);
    VM4();
    BAR();

    // ph5: read buf1 k0; stage buf0 B-lo (tile 2t+2); Q1
#pragma unroll
    for (int i = 0; i < 8; ++i) a0[i] = FRA(1, i, 0);
#pragma unroll
    for (int i = 0; i < 4; ++i) b0[i] = FRB(1, i, 0);
    STG(32768, Bb + c2);
    BAR(); LGKM0();
    QMFMA(a0, b0, 0);
    BAR();

    // ph6: read buf1 k1; stage buf0 B-hi; Q2
#pragma unroll
    for (int i = 0; i < 8; ++i) a1[i] = FRA(1, i, 1);
#pragma unroll
    for (int i = 0; i < 4; ++i) b1[i] = FRB(1, i, 1);
    STG(49152, Bb + hiO + c2);
    BAR(); LGKM0();
    QMFMA(a0, b0, 4);
    BAR();

    // ph7: stage buf1 A-lo (tile 2t+3); Q3
    STG(65536, Ab + c3);
    BAR(); LGKM0();
    QMFMA(a1, b1, 0);
    BAR();

    // ph8: stage buf1 A-hi; Q4; counted vmcnt before next buf0 reads
    STG(81920, Ab + hiO + c3);
    BAR(); LGKM0();
    QMFMA(a1, b1, 4);
    VM4();
    BAR();
  }

  // ---- epilogue: +bias, f32 store ----
#pragma unroll
  for (int ni = 0; ni < 4; ++ni) {
    const size_t col = n0 + wc * 64 + ni * 16 + r16;
    const float bv = bias[col];
#pragma unroll
    for (int mi = 0; mi < 8; ++mi) {
      const size_t row0 = m0 + wr * 128 + mi * 16 + kg * 4;
#pragma unroll
      for (int j = 0; j < 4; ++j)
        C[(row0 + j) * N + col] = acc[mi][ni][j] + bv;
    }
  }
}

// ---------- round-1 128x128 kernel (fallback, known-good) ----------

__global__ __launch_bounds__(256) void gemm_bin(
    const uint16_t* __restrict__ A, const uint16_t* __restrict__ B,
    const float* __restrict__ bias, float* __restrict__ C,
    int M, int N, int K) {
  constexpr int BK = 32;
  __shared__ alignas(16) uint16_t lA[128 * BK];
  __shared__ alignas(16) uint16_t lB[128 * BK];
  const int tid = threadIdx.x;
  const int lane = tid & 63;
  const int wid = tid >> 6;
  const int wr = wid >> 1, wc = wid & 1;
  const int r16 = lane & 15, kg = lane >> 4;
  const int m0 = blockIdx.y * 128, n0 = blockIdx.x * 128;
  f32x4 acc[4][4] = {};
  for (int k0 = 0; k0 < K; k0 += BK) {
    __syncthreads();
#pragma unroll
    for (int p = 0; p < 2; ++p) {
      int idx = p * 256 + tid;
      int row = idx >> 2;
      int col = (idx & 3) * 8;
      gl16(A + (size_t)(m0 + row) * K + k0 + col, lA + p * 2048 + wid * 512);
      gl16(B + (size_t)(n0 + row) * K + k0 + col, lB + p * 2048 + wid * 512);
    }
    __syncthreads();
    bf16x8 af[4], bg[4];
#pragma unroll
    for (int i = 0; i < 4; ++i)
      af[i] = *reinterpret_cast<const bf16x8*>(lA + (wr * 64 + i * 16 + r16) * BK + kg * 8);
#pragma unroll
    for (int i = 0; i < 4; ++i)
      bg[i] = *reinterpret_cast<const bf16x8*>(lB + (wc * 64 + i * 16 + r16) * BK + kg * 8);
#pragma unroll
    for (int mi = 0; mi < 4; ++mi)
#pragma unroll
      for (int ni = 0; ni < 4; ++ni)
        acc[mi][ni] = __builtin_amdgcn_mfma_f32_16x16x32_bf16(af[mi], bg[ni], acc[mi][ni], 0, 0, 0);
  }
#pragma unroll
  for (int ni = 0; ni < 4; ++ni) {
    int col = n0 + wc * 64 + ni * 16 + r16;
    float bv = bias[col];
#pragma unroll
    for (int mi = 0; mi < 4; ++mi) {
      int row0 = m0 + wr * 64 + mi * 16 + kg * 4;
#pragma unroll
      for (int j = 0; j < 4; ++j)
        C[(size_t)(row0 + j) * N + col] = acc[mi][ni][j] + bv;
    }
  }
}

__global__ void gemm_naive(const float* __restrict__ x, const float* __restrict__ w,
                           const float* __restrict__ b, float* __restrict__ out,
                           int M, int N, int K) {
  int n = blockIdx.x * blockDim.x + threadIdx.x;
  int m = blockIdx.y;
  if (n >= N || m >= M) return;
  float acc = 0.f;
  for (int k = 0; k < K; ++k) {
    float wv = w[(size_t)n * K + k];
    float s = (wv > 0.f) ? 1.f : ((wv < 0.f) ? -1.f : 0.f);
    acc += x[(size_t)m * K + k] * s;
  }
  out[(size_t)m * N + n] = acc + b[n];
}

extern "C" void kernel_launch(void* const* d_in, const int* in_sizes, int n_in,
                              void* d_out, int out_size, void* d_ws, size_t ws_size,
                              hipStream_t stream) {
  const float* x = (const float*)d_in[0];
  const float* w = (const float*)d_in[1];
  const float* b = (const float*)d_in[2];
  float* out = (float*)d_out;

  const int N = in_sizes[2];
  const int K = in_sizes[1] / N;
  const int M = in_sizes[0] / K;

  const size_t need = ((size_t)M * K + (size_t)N * K) * sizeof(uint16_t);
  if (ws_size < need) {
    hipLaunchKernelGGL(gemm_naive, dim3((N + 255) / 256, M), dim3(256), 0, stream,
                       x, w, b, out, M, N, K);
    return;
  }

  uint16_t* Xb = (uint16_t*)d_ws;
  uint16_t* Wb = Xb + (size_t)M * K;

  hipLaunchKernelGGL(cvt_prep, dim3(2048), dim3(256), 0, stream,
                     (const uint4*)x, (uint4*)Xb, (M * K) / 8,
                     (const uint4*)w, (uint4*)Wb, (N * K) / 8);

  const bool big_ok = (M % 256 == 0) && (N % 256 == 0) && (K % 128 == 0) &&
                      (((M / 256) * (N / 256)) % 8 == 0);
  if (big_ok) {
    hipLaunchKernelGGL(gemm256, dim3((M / 256) * (N / 256)), dim3(512), 0, stream,
                       Xb, Wb, b, out, M, N, K);
  } else {
    hipLaunchKernelGGL(gemm_bin, dim3(N / 128, M / 128), dim3(256), 0, stream,
                       Xb, Wb, b, out, M, N, K);
  }
}

// Round 4
// 146.987 us; speedup vs baseline: 1.4022x; 1.0651x over previous
//
#include <hip/hip_runtime.h>
#include <hip/hip_bf16.h>
#include <stdint.h>

typedef __bf16 bf16x8 __attribute__((ext_vector_type(8)));
typedef float  f32x4  __attribute__((ext_vector_type(4)));

// ---------- helpers ----------

__device__ __forceinline__ uint32_t rn2_bf16(uint32_t lo, uint32_t hi) {
  uint32_t rlo = (lo + 0x7FFFu + ((lo >> 16) & 1u)) >> 16;
  uint32_t rhi = (hi + 0x7FFFu + ((hi >> 16) & 1u)) >> 16;
  return (rhi << 16) | (rlo & 0xFFFFu);
}

__device__ __forceinline__ uint32_t sign2_bf16(uint32_t lo, uint32_t hi) {
  uint32_t slo = (lo & 0x7FFFFFFFu) ? (0x3F80u | ((lo >> 16) & 0x8000u)) : 0u;
  uint32_t shi = (hi & 0x7FFFFFFFu) ? (0x3F80u | ((hi >> 16) & 0x8000u)) : 0u;
  return (shi << 16) | slo;
}

__device__ __forceinline__ void gl16(const void* g, void* l) {
  __builtin_amdgcn_global_load_lds(
      (const __attribute__((address_space(1))) uint32_t*)g,
      (__attribute__((address_space(3))) uint32_t*)l,
      16, 0, 0);
}

// ---------- fused prep kernel: X -> bf16 (RN), W -> sign bf16 ----------

__global__ void cvt_prep(const uint4* __restrict__ x, uint4* __restrict__ xo, int nx8,
                         const uint4* __restrict__ w, uint4* __restrict__ wo, int nw8) {
  int stride = gridDim.x * blockDim.x;
  int total = nx8 + nw8;
  for (int i = blockIdx.x * blockDim.x + threadIdx.x; i < total; i += stride) {
    if (i < nx8) {
      uint4 a = x[2 * i + 0];
      uint4 b = x[2 * i + 1];
      uint4 o;
      o.x = rn2_bf16(a.x, a.y);
      o.y = rn2_bf16(a.z, a.w);
      o.z = rn2_bf16(b.x, b.y);
      o.w = rn2_bf16(b.z, b.w);
      xo[i] = o;
    } else {
      int j = i - nx8;
      uint4 a = w[2 * j + 0];
      uint4 b = w[2 * j + 1];
      uint4 o;
      o.x = sign2_bf16(a.x, a.y);
      o.y = sign2_bf16(a.z, a.w);
      o.z = sign2_bf16(b.x, b.y);
      o.w = sign2_bf16(b.z, b.w);
      wo[j] = o;
    }
  }
}

// ---------- 256x256 8-phase GEMM, read-ahead pipelined ----------
// C[M][N] = A[M][K] * B[N][K]^T + bias.  BM=BN=256, BK=64, 8 waves (2Mx4N).
// LDS 128 KiB: buf d at d*65536; A tile [256][64]bf16 at +0, B at +32768.
// Swizzle byte ^= ((byte>>7)&7)<<4 (R3-verified: bank conflicts = 0).
// Pipelining: phase p issues ds_reads consumed by phase p+1's MFMA, so the
// LDS-read pipe overlaps the matrix pipe (R3's alternating-window 45% ceiling).
// One raw s_barrier per phase; compiler emits counted lgkmcnt at frag use.
// Stage-after-read rule (STG(X) >= last-consume(X)+1): A0:ph4->STG ph5;
// B0:ph3->ph4; A1:ph8->ph1'; B1:ph7->ph8. VM0 at ph3/ph7 drains exactly the
// incoming tile's 8 loads (2-3 phases old > HBM latency -> ~0 stall).

#define BARX()  asm volatile("s_barrier" ::: "memory")
#define VM0()   asm volatile("s_waitcnt vmcnt(0)" ::: "memory")
#define VMN4()  asm volatile("s_waitcnt vmcnt(4)" ::: "memory")
#define SWZ(x)  ((x) ^ ((((x) >> 7) & 7) << 4))

__global__ __launch_bounds__(512, 2) void gemm256(
    const uint16_t* __restrict__ A,  // [M][K] bf16 bits
    const uint16_t* __restrict__ B,  // [N][K] bf16 bits (sign values)
    const float* __restrict__ bias,  // [N]
    float* __restrict__ C,           // [M][N] f32
    int M, int N, int K) {
  __shared__ alignas(16) uint8_t L[131072];
  uint8_t* Lb = L;

  const int tid  = threadIdx.x;
  const int lane = tid & 63;
  const int w    = tid >> 6;
  const int wr   = w >> 2;        // 0..1  -> M rows [wr*128, +128)
  const int wc   = w & 3;         // 0..3  -> N cols [wc*64, +64)
  const int r16  = lane & 15;
  const int kg   = lane >> 4;

  // bijective XCD swizzle (nwg % 8 == 0 guaranteed by launcher)
  const int nbx = N >> 8;
  const int nwg = nbx * (M >> 8);
  const int bid = blockIdx.x;
  const int swb = (bid & 7) * (nwg >> 3) + (bid >> 3);
  const size_t m0 = (size_t)(swb / nbx) << 8;
  const size_t n0 = (size_t)(swb % nbx) << 8;

  const int NT = K >> 6;              // BK=64 tiles
  const size_t rowB = (size_t)K * 2;  // global row stride in bytes

  // staging: per-lane pre-swizzled global source offsets (16B/lane)
  const int o0 = (w << 10) + (lane << 4);
  const int o1 = o0 + 8192;
  const int s0 = SWZ(o0);
  const int s1 = SWZ(o1);
  const size_t g0 = (size_t)(s0 >> 7) * rowB + (s0 & 127);
  const size_t g1 = (size_t)(s1 >> 7) * rowB + (s1 & 127);
  const char* Ab = (const char*)A + m0 * rowB;
  const char* Bb = (const char*)B + n0 * rowB;
  const size_t hiO = (size_t)128 * rowB;  // +128 rows (second half)
  const int wB = w << 10;

  // fragment lane bases (bytes within a 32KB tile region)
  const int laneA = (wr * 128 + r16) * 128 + kg * 16;
  const int laneB = (wc * 64 + r16) * 128 + kg * 16;

#define STG(LOFF, SRC) do { \
    gl16((SRC) + g0, Lb + (LOFF) + wB); \
    gl16((SRC) + g1, Lb + (LOFF) + 8192 + wB); } while (0)

#define FRA(d, mi, ks) (*reinterpret_cast<const bf16x8*>( \
    Lb + (d) * 65536 + SWZ(laneA + (mi) * 2048 + (ks) * 64)))
#define FRB(d, ni, ks) (*reinterpret_cast<const bf16x8*>( \
    Lb + (d) * 65536 + 32768 + SWZ(laneB + (ni) * 2048 + (ks) * 64)))

  f32x4 acc[8][4] = {};

#define QM(A4, B4, MB) do { \
    __builtin_amdgcn_s_setprio(1); \
    _Pragma("unroll") \
    for (int mi2 = 0; mi2 < 4; ++mi2) \
      _Pragma("unroll") \
      for (int ni = 0; ni < 4; ++ni) \
        acc[(MB) + mi2][ni] = __builtin_amdgcn_mfma_f32_16x16x32_bf16( \
            A4[mi2], B4[ni], acc[(MB) + mi2][ni], 0, 0, 0); \
    __builtin_amdgcn_s_setprio(0); } while (0)

#define RDA(DST, d, base, ks) do { \
    _Pragma("unroll") \
    for (int i = 0; i < 4; ++i) DST[i] = FRA(d, (base) + i, ks); } while (0)
#define RDB(DST, d, ks) do { \
    _Pragma("unroll") \
    for (int i = 0; i < 4; ++i) DST[i] = FRB(d, i, ks); } while (0)

  // ---- prologue: tile0 (A+B) -> buf0, tile1 B -> buf1 ----
  STG(0,      Ab);            // A0-lo
  STG(16384,  Ab + hiO);      // A0-hi
  STG(32768,  Bb);            // B0-lo
  STG(49152,  Bb + hiO);      // B0-hi
  STG(98304,  Bb + 128);      // B1-lo  (tile 1 = byte col offset 128)
  STG(114688, Bb + hiO + 128);// B1-hi
  VMN4();   // tile0's 8 landed; B1's 4 in flight
  BARX();

  bf16x8 aLo[4], aHi[4], bA[4], bB[4];
  RDA(aLo, 0, 0, 0);
  RDB(bA, 0, 0);

  const int T = K >> 7;  // iterations of 2 K-tiles
  for (int t = 0; t < T; ++t) {
    const size_t c1 = (size_t)(2 * t + 1) * 128;
    const int k2i = 2 * t + 2, k3i = 2 * t + 3;
    const size_t c2 = (size_t)(k2i < NT ? k2i : NT - 1) * 128;
    const size_t c3 = (size_t)(k3i < NT ? k3i : NT - 1) * 128;

    // ph1: MFMA(aLo,bA); read buf0 k0-hi; stage A(t1)->buf1-A
    QM(aLo, bA, 0);
    RDA(aHi, 0, 4, 0);
    STG(65536, Ab + c1);
    STG(81920, Ab + hiO + c1);
    BARX();

    // ph2: MFMA(aHi,bA); read buf0 k1-lo + B k1
    QM(aHi, bA, 4);
    RDA(aLo, 0, 0, 1);
    RDB(bB, 0, 1);
    BARX();

    // ph3: MFMA(aLo,bB); read buf0 k1-hi; VM0 drains t1 (B@ph8prev, A@ph1)
    QM(aLo, bB, 0);
    RDA(aHi, 0, 4, 1);
    VM0();
    BARX();

    // ph4: MFMA(aHi,bB); read buf1 k0-lo + B k0; stage B(t2)->buf0-B
    QM(aHi, bB, 4);
    RDA(aLo, 1, 0, 0);
    RDB(bA, 1, 0);
    STG(32768, Bb + c2);
    STG(49152, Bb + hiO + c2);
    BARX();

    // ph5: MFMA(aLo,bA); read buf1 k0-hi; stage A(t2)->buf0-A
    QM(aLo, bA, 0);
    RDA(aHi, 1, 4, 0);
    STG(0, Ab + c2);
    STG(16384, Ab + hiO + c2);
    BARX();

    // ph6: MFMA(aHi,bA); read buf1 k1-lo + B k1
    QM(aHi, bA, 4);
    RDA(aLo, 1, 0, 1);
    RDB(bB, 1, 1);
    BARX();

    // ph7: MFMA(aLo,bB); read buf1 k1-hi; VM0 drains t2 (B@ph4, A@ph5)
    QM(aLo, bB, 0);
    RDA(aHi, 1, 4, 1);
    VM0();
    BARX();

    // ph8: MFMA(aHi,bB); read buf0' k0-lo + B k0; stage B(t3)->buf1-B
    QM(aHi, bB, 4);
    RDA(aLo, 0, 0, 0);
    RDB(bA, 0, 0);
    STG(98304, Bb + c3);
    STG(114688, Bb + hiO + c3);
    BARX();
  }

  // ---- epilogue: +bias, f32 store ----
#pragma unroll
  for (int ni = 0; ni < 4; ++ni) {
    const size_t col = n0 + wc * 64 + ni * 16 + r16;
    const float bv = bias[col];
#pragma unroll
    for (int mi = 0; mi < 8; ++mi) {
      const size_t row0 = m0 + wr * 128 + mi * 16 + kg * 4;
#pragma unroll
      for (int j = 0; j < 4; ++j)
        C[(row0 + j) * N + col] = acc[mi][ni][j] + bv;
    }
  }
}

// ---------- round-1 128x128 kernel (fallback, known-good) ----------

__global__ __launch_bounds__(256) void gemm_bin(
    const uint16_t* __restrict__ A, const uint16_t* __restrict__ B,
    const float* __restrict__ bias, float* __restrict__ C,
    int M, int N, int K) {
  constexpr int BK = 32;
  __shared__ alignas(16) uint16_t lA[128 * BK];
  __shared__ alignas(16) uint16_t lB[128 * BK];
  const int tid = threadIdx.x;
  const int lane = tid & 63;
  const int wid = tid >> 6;
  const int wr = wid >> 1, wc = wid & 1;
  const int r16 = lane & 15, kg = lane >> 4;
  const int m0 = blockIdx.y * 128, n0 = blockIdx.x * 128;
  f32x4 acc[4][4] = {};
  for (int k0 = 0; k0 < K; k0 += BK) {
    __syncthreads();
#pragma unroll
    for (int p = 0; p < 2; ++p) {
      int idx = p * 256 + tid;
      int row = idx >> 2;
      int col = (idx & 3) * 8;
      gl16(A + (size_t)(m0 + row) * K + k0 + col, lA + p * 2048 + wid * 512);
      gl16(B + (size_t)(n0 + row) * K + k0 + col, lB + p * 2048 + wid * 512);
    }
    __syncthreads();
    bf16x8 af[4], bg[4];
#pragma unroll
    for (int i = 0; i < 4; ++i)
      af[i] = *reinterpret_cast<const bf16x8*>(lA + (wr * 64 + i * 16 + r16) * BK + kg * 8);
#pragma unroll
    for (int i = 0; i < 4; ++i)
      bg[i] = *reinterpret_cast<const bf16x8*>(lB + (wc * 64 + i * 16 + r16) * BK + kg * 8);
#pragma unroll
    for (int mi = 0; mi < 4; ++mi)
#pragma unroll
      for (int ni = 0; ni < 4; ++ni)
        acc[mi][ni] = __builtin_amdgcn_mfma_f32_16x16x32_bf16(af[mi], bg[ni], acc[mi][ni], 0, 0, 0);
  }
#pragma unroll
  for (int ni = 0; ni < 4; ++ni) {
    int col = n0 + wc * 64 + ni * 16 + r16;
    float bv = bias[col];
#pragma unroll
    for (int mi = 0; mi < 4; ++mi) {
      int row0 = m0 + wr * 64 + mi * 16 + kg * 4;
#pragma unroll
      for (int j = 0; j < 4; ++j)
        C[(size_t)(row0 + j) * N + col] = acc[mi][ni][j] + bv;
    }
  }
}

__global__ void gemm_naive(const float* __restrict__ x, const float* __restrict__ w,
                           const float* __restrict__ b, float* __restrict__ out,
                           int M, int N, int K) {
  int n = blockIdx.x * blockDim.x + threadIdx.x;
  int m = blockIdx.y;
  if (n >= N || m >= M) return;
  float acc = 0.f;
  for (int k = 0; k < K; ++k) {
    float wv = w[(size_t)n * K + k];
    float s = (wv > 0.f) ? 1.f : ((wv < 0.f) ? -1.f : 0.f);
    acc += x[(size_t)m * K + k] * s;
  }
  out[(size_t)m * N + n] = acc + b[n];
}

extern "C" void kernel_launch(void* const* d_in, const int* in_sizes, int n_in,
                              void* d_out, int out_size, void* d_ws, size_t ws_size,
                              hipStream_t stream) {
  const float* x = (const float*)d_in[0];
  const float* w = (const float*)d_in[1];
  const float* b = (const float*)d_in[2];
  float* out = (float*)d_out;

  const int N = in_sizes[2];
  const int K = in_sizes[1] / N;
  const int M = in_sizes[0] / K;

  const size_t need = ((size_t)M * K + (size_t)N * K) * sizeof(uint16_t);
  if (ws_size < need) {
    hipLaunchKernelGGL(gemm_naive, dim3((N + 255) / 256, M), dim3(256), 0, stream,
                       x, w, b, out, M, N, K);
    return;
  }

  uint16_t* Xb = (uint16_t*)d_ws;
  uint16_t* Wb = Xb + (size_t)M * K;

  hipLaunchKernelGGL(cvt_prep, dim3(2048), dim3(256), 0, stream,
                     (const uint4*)x, (uint4*)Xb, (M * K) / 8,
                     (const uint4*)w, (uint4*)Wb, (N * K) / 8);

  const bool big_ok = (M % 256 == 0) && (N % 256 == 0) && (K % 256 == 0) &&
                      (((M / 256) * (N / 256)) % 8 == 0);
  if (big_ok) {
    hipLaunchKernelGGL(gemm256, dim3((M / 256) * (N / 256)), dim3(512), 0, stream,
                       Xb, Wb, b, out, M, N, K);
  } else {
    hipLaunchKernelGGL(gemm_bin, dim3(N / 128, M / 128), dim3(256), 0, stream,
                       Xb, Wb, b, out, M, N, K);
  }
}